// Round 10
// baseline (223.489 us; speedup 1.0000x reference)
//
#include <hip/hip_runtime.h>
#include <hip/hip_bf16.h>
#include <math.h>

#define D_K  512
#define NROW 8192
#define BM   128
#define BN   128
#define BK   64

typedef __attribute__((ext_vector_type(8))) short bf16x8;
typedef __attribute__((ext_vector_type(4))) float f32x4;

#if __has_builtin(__builtin_amdgcn_rsqf)
#define RSQ(x) __builtin_amdgcn_rsqf(x)
#else
#define RSQ(x) rsqrtf(x)
#endif

// f32 -> bf16 round-to-nearest-even
__device__ __forceinline__ unsigned short f2bf(float f) {
    unsigned int u = __float_as_uint(f);
    unsigned int r = (u + 0x7FFFu + ((u >> 16) & 1u)) >> 16;
    return (unsigned short)r;
}

// async global->LDS, 16B per lane (wave-uniform LDS base; HW writes base + lane*16)
__device__ __forceinline__ void load_lds16(const unsigned short* g, unsigned short* l) {
    __builtin_amdgcn_global_load_lds(
        (const __attribute__((address_space(1))) unsigned int*)g,
        (__attribute__((address_space(3))) unsigned int*)l,
        16, 0, 0);
}

// ---------------- prep: f32 -> bf16 + per-row epilogue scalars ----------------
__global__ void prep_kernel(const float* __restrict__ xin, const float* __restrict__ yin,
                            unsigned short* __restrict__ xb, unsigned short* __restrict__ yb,
                            float* __restrict__ px0, float* __restrict__ px1,
                            float* __restrict__ py0, float* __restrict__ py1)
{
    const int row   = blockIdx.x;
    const int which = blockIdx.y;
    const float* src = (which ? yin : xin) + (size_t)row * D_K;
    unsigned short* dst = (which ? yb : xb) + (size_t)row * D_K;
    const int t = threadIdx.x;

    float2 v = ((const float2*)src)[t];
    ushort2 b; b.x = f2bf(v.x); b.y = f2bf(v.y);
    ((ushort2*)dst)[t] = b;

    float s = v.x * v.x + v.y * v.y;
    for (int o = 32; o > 0; o >>= 1) s += __shfl_down(s, o, 64);
    __shared__ float red[4];
    if ((t & 63) == 0) red[t >> 6] = s;
    __syncthreads();
    if (t == 0) {
        float tot = red[0] + red[1] + red[2] + red[3];
        float c0 = tot * (1.0f / D_K);
        float a0 = 1.0f + 2.0f * c0;
        float c1 = 0.636619772367581343f * asinf(2.0f * c0 / a0);
        float a1 = 1.0f + 2.0f * c1;
        if (which) {
            py0[row] = 1.0f / sqrtf(a0);
            py1[row] = 1.0f / sqrtf(a1);
        } else {
            px0[row] = 2.0f / sqrtf(a0);
            px1[row] = 2.0f / sqrtf(a1);
        }
    }
}

// one Erf layer + Dense. s = 2*rsqrt(prod), sC = (2/pi)*s. deg-7 odd asin poly
// (|ratio| < 2/3 structurally; truncation < 1e-7 at the observed |ratio| <= 0.25).
__device__ __forceinline__ void layer_step(float& nngp, float& ntk, float s, float sC) {
    float r = nngp * s;
    float u = r * r;
    float p = fmaf(u, 0.028420525f, 0.047746483f);
    p = fmaf(u, p, 0.106103295f);
    p = fmaf(u, p, 0.636619772f);
    float nn = r * p;
    float rv = RSQ(1.0f - u);
    ntk = fmaf(ntk, sC * rv, nn);
    nngp = nn;
}

// ---------------- main: bf16 MFMA GEMM + fused NTK epilogue ----------------
// 128x128 tile, 4 waves (2x2 of 64x64), 16x16x32 MFMA, natural 2D grid.
// PLAIN scattered stores (r1/r3-verified clean: W~307MB vs nt's 655MB).
__global__ void ntk_kernel(const unsigned short* __restrict__ xb,
                           const unsigned short* __restrict__ yb,
                           const float* __restrict__ px0, const float* __restrict__ px1,
                           const float* __restrict__ py0, const float* __restrict__ py1,
                           float* __restrict__ out)
{
    __shared__ unsigned short As[BM * BK];  // 16 KiB
    __shared__ unsigned short Bs[BN * BK];  // 16 KiB

    const int tid  = threadIdx.x;
    const int lane = tid & 63;
    const int wid  = tid >> 6;
    const int wr   = wid >> 1;
    const int wc   = wid & 1;

    const int rowBase = blockIdx.y * BM;    // natural mapping (measured-clean traffic)
    const int colBase = blockIdx.x * BN;
    const int l15 = lane & 15;
    const int lg  = lane >> 4;

    f32x4 acc[4][4];
    #pragma unroll
    for (int m = 0; m < 4; m++)
        #pragma unroll
        for (int n = 0; n < 4; n++)
            acc[m][n] = (f32x4){0.f, 0.f, 0.f, 0.f};

    for (int ks = 0; ks < D_K; ks += BK) {
        __syncthreads();
        // stage A + B: chunk c -> row = c>>3, phys slot t = c&7 holds source chunk t^(row&7)
        #pragma unroll
        for (int r = 0; r < 4; r++) {
            int base = r * 256 + wid * 64;
            int cidx = base + lane;
            int row  = cidx >> 3;
            int c    = ((cidx & 7) ^ (row & 7)) * 8;
            load_lds16(xb + (size_t)(rowBase + row) * D_K + ks + c, &As[base * 8]);
            load_lds16(yb + (size_t)(colBase + row) * D_K + ks + c, &Bs[base * 8]);
        }
        __syncthreads();

        bf16x8 af[2][4], bfr[2][4];
        #pragma unroll
        for (int s = 0; s < 2; s++) {
            #pragma unroll
            for (int m = 0; m < 4; m++) {
                int rowA = wr * 64 + m * 16 + l15;
                af[s][m]  = *(const bf16x8*)&As[rowA * BK + (((s * 4 + lg) ^ (rowA & 7)) * 8)];
                int rowB = wc * 64 + m * 16 + l15;
                bfr[s][m] = *(const bf16x8*)&Bs[rowB * BK + (((s * 4 + lg) ^ (rowB & 7)) * 8)];
            }
        }
        __builtin_amdgcn_s_setprio(1);
        #pragma unroll
        for (int s = 0; s < 2; s++)
            #pragma unroll
            for (int m = 0; m < 4; m++)
                #pragma unroll
                for (int n = 0; n < 4; n++)
                    acc[m][n] = __builtin_amdgcn_mfma_f32_16x16x32_bf16(
                        af[s][m], bfr[s][n], acc[m][n], 0, 0, 0);
        __builtin_amdgcn_s_setprio(0);
    }

    // fused epilogue. C/D layout: col = lane&15, row = (lane>>4)*4 + reg
    float py0v[4], py1v[4], py0C[4], py1C[4];
    int   colv[4];
    #pragma unroll
    for (int n = 0; n < 4; n++) {
        int col = colBase + wc * 64 + n * 16 + l15;
        colv[n] = col;
        py0v[n] = py0[col];
        py1v[n] = py1[col];
        py0C[n] = 0.636619772f * py0v[n];
        py1C[n] = 0.636619772f * py1v[n];
    }
    #pragma unroll
    for (int m = 0; m < 4; m++) {
        int row0 = rowBase + wr * 64 + m * 16 + lg * 4;
        #pragma unroll
        for (int j = 0; j < 4; j++) {
            int row = row0 + j;
            float a0 = px0[row], a1 = px1[row];
            #pragma unroll
            for (int n = 0; n < 4; n++) {
                float nngp = acc[m][n][j] * (1.0f / D_K);
                float ntk = nngp;
                layer_step(nngp, ntk, a0 * py0v[n], a0 * py0C[n]);
                layer_step(nngp, ntk, a1 * py1v[n], a1 * py1C[n]);
                out[(size_t)row * NROW + colv[n]] = ntk;   // plain store (clean writeback)
            }
        }
    }
}

extern "C" void kernel_launch(void* const* d_in, const int* in_sizes, int n_in,
                              void* d_out, int out_size, void* d_ws, size_t ws_size,
                              hipStream_t stream)
{
    const float* x = (const float*)d_in[0];
    const float* y = (const float*)d_in[1];
    float* out = (float*)d_out;

    char* ws = (char*)d_ws;
    unsigned short* xb = (unsigned short*)ws;
    unsigned short* yb = (unsigned short*)(ws + (size_t)8 * 1024 * 1024);
    float* px0 = (float*)(ws + (size_t)16 * 1024 * 1024);
    float* px1 = px0 + NROW;
    float* py0 = px1 + NROW;
    float* py1 = py0 + NROW;

    dim3 pgrid(NROW, 2);
    prep_kernel<<<pgrid, 256, 0, stream>>>(x, y, xb, yb, px0, px1, py0, py1);

    dim3 grid(NROW / BN, NROW / BM);
    ntk_kernel<<<grid, 256, 0, stream>>>(xb, yb, px0, px1, py0, py1, out);
}

// Round 11
// 136.099 us; speedup vs baseline: 1.6421x; 1.6421x over previous
//
#include <hip/hip_runtime.h>
#include <hip/hip_bf16.h>
#include <math.h>

#define D_K  512
#define NROW 8192
#define BM   128
#define BN   128
#define BK   64

typedef __attribute__((ext_vector_type(8))) short bf16x8;
typedef __attribute__((ext_vector_type(4))) float f32x4;

#if __has_builtin(__builtin_amdgcn_rsqf)
#define RSQ(x) __builtin_amdgcn_rsqf(x)
#else
#define RSQ(x) rsqrtf(x)
#endif

// f32 -> bf16 round-to-nearest-even
__device__ __forceinline__ unsigned short f2bf(float f) {
    unsigned int u = __float_as_uint(f);
    unsigned int r = (u + 0x7FFFu + ((u >> 16) & 1u)) >> 16;
    return (unsigned short)r;
}

// async global->LDS, 16B per lane (wave-uniform LDS base; HW writes base + lane*16)
__device__ __forceinline__ void load_lds16(const unsigned short* g, unsigned short* l) {
    __builtin_amdgcn_global_load_lds(
        (const __attribute__((address_space(1))) unsigned int*)g,
        (__attribute__((address_space(3))) unsigned int*)l,
        16, 0, 0);
}

// ---------------- prep: f32 -> bf16 + per-row epilogue scalars ----------------
__global__ void prep_kernel(const float* __restrict__ xin, const float* __restrict__ yin,
                            unsigned short* __restrict__ xb, unsigned short* __restrict__ yb,
                            float* __restrict__ px0, float* __restrict__ px1,
                            float* __restrict__ py0, float* __restrict__ py1)
{
    const int row   = blockIdx.x;
    const int which = blockIdx.y;
    const float* src = (which ? yin : xin) + (size_t)row * D_K;
    unsigned short* dst = (which ? yb : xb) + (size_t)row * D_K;
    const int t = threadIdx.x;

    float2 v = ((const float2*)src)[t];
    ushort2 b; b.x = f2bf(v.x); b.y = f2bf(v.y);
    ((ushort2*)dst)[t] = b;

    float s = v.x * v.x + v.y * v.y;
    for (int o = 32; o > 0; o >>= 1) s += __shfl_down(s, o, 64);
    __shared__ float red[4];
    if ((t & 63) == 0) red[t >> 6] = s;
    __syncthreads();
    if (t == 0) {
        float tot = red[0] + red[1] + red[2] + red[3];
        float c0 = tot * (1.0f / D_K);
        float a0 = 1.0f + 2.0f * c0;
        float c1 = 0.636619772367581343f * asinf(2.0f * c0 / a0);
        float a1 = 1.0f + 2.0f * c1;
        if (which) {
            py0[row] = 1.0f / sqrtf(a0);
            py1[row] = 1.0f / sqrtf(a1);
        } else {
            px0[row] = 2.0f / sqrtf(a0);
            px1[row] = 2.0f / sqrtf(a1);
        }
    }
}

// one Erf layer + Dense. s = 2*rsqrt(prod), sC = (2/pi)*s. deg-7 odd asin poly
// (|ratio| < 2/3 structurally; truncation < 1e-7 at the observed |ratio| <= 0.25).
__device__ __forceinline__ void layer_step(float& nngp, float& ntk, float s, float sC) {
    float r = nngp * s;
    float u = r * r;
    float p = fmaf(u, 0.028420525f, 0.047746483f);
    p = fmaf(u, p, 0.106103295f);
    p = fmaf(u, p, 0.636619772f);
    float nn = r * p;
    float rv = RSQ(1.0f - u);
    ntk = fmaf(ntk, sC * rv, nn);
    nngp = nn;
}

// ---------------- main: bf16 MFMA GEMM + fused NTK epilogue ----------------
// 128x128 tile, 4 waves (2x2 of 64x64), 16x16x32 MFMA.
// EXACT r4 config (best measured: 133.4 us): XCD-banded block swizzle + nt stores
// + deg-7 lean epilogue + XOR-swizzled LDS. Only change vs r4: setprio removed
// (m190: setprio slightly negative on 2-barrier GEMM structures).
__global__ void ntk_kernel(const unsigned short* __restrict__ xb,
                           const unsigned short* __restrict__ yb,
                           const float* __restrict__ px0, const float* __restrict__ px1,
                           const float* __restrict__ py0, const float* __restrict__ py1,
                           float* __restrict__ out)
{
    __shared__ unsigned short As[BM * BK];  // 16 KiB
    __shared__ unsigned short Bs[BN * BK];  // 16 KiB

    const int tid  = threadIdx.x;
    const int lane = tid & 63;
    const int wid  = tid >> 6;
    const int wr   = wid >> 1;
    const int wc   = wid & 1;

    // XCD-banded swizzle: xcd = bid&7 owns row-tiles [xcd*8, xcd*8+8) x all col-tiles;
    // within XCD, 8 consecutive blocks share one B-panel (L2 reuse), A-band stays hot,
    // and each XCD's write-back stream covers a contiguous 32 MB output region.
    const int bid = blockIdx.x;
    const int xcd = bid & 7;
    const int idx = bid >> 3;
    const int by  = xcd * 8 + (idx & 7);
    const int bx  = idx >> 3;
    const int rowBase = by * BM;
    const int colBase = bx * BN;
    const int l15 = lane & 15;
    const int lg  = lane >> 4;

    f32x4 acc[4][4];
    #pragma unroll
    for (int m = 0; m < 4; m++)
        #pragma unroll
        for (int n = 0; n < 4; n++)
            acc[m][n] = (f32x4){0.f, 0.f, 0.f, 0.f};

    for (int ks = 0; ks < D_K; ks += BK) {
        __syncthreads();
        // stage A + B: chunk c -> row = c>>3, phys slot t = c&7 holds source chunk t^(row&7)
        #pragma unroll
        for (int r = 0; r < 4; r++) {
            int base = r * 256 + wid * 64;
            int cidx = base + lane;
            int row  = cidx >> 3;
            int c    = ((cidx & 7) ^ (row & 7)) * 8;
            load_lds16(xb + (size_t)(rowBase + row) * D_K + ks + c, &As[base * 8]);
            load_lds16(yb + (size_t)(colBase + row) * D_K + ks + c, &Bs[base * 8]);
        }
        __syncthreads();

        bf16x8 af[2][4], bfr[2][4];
        #pragma unroll
        for (int s = 0; s < 2; s++) {
            #pragma unroll
            for (int m = 0; m < 4; m++) {
                int rowA = wr * 64 + m * 16 + l15;
                af[s][m]  = *(const bf16x8*)&As[rowA * BK + (((s * 4 + lg) ^ (rowA & 7)) * 8)];
                int rowB = wc * 64 + m * 16 + l15;
                bfr[s][m] = *(const bf16x8*)&Bs[rowB * BK + (((s * 4 + lg) ^ (rowB & 7)) * 8)];
            }
        }
        #pragma unroll
        for (int s = 0; s < 2; s++)
            #pragma unroll
            for (int m = 0; m < 4; m++)
                #pragma unroll
                for (int n = 0; n < 4; n++)
                    acc[m][n] = __builtin_amdgcn_mfma_f32_16x16x32_bf16(
                        af[s][m], bfr[s][n], acc[m][n], 0, 0, 0);
    }

    // fused epilogue. C/D layout: col = lane&15, row = (lane>>4)*4 + reg
    float py0v[4], py1v[4], py0C[4], py1C[4];
    int   colv[4];
    #pragma unroll
    for (int n = 0; n < 4; n++) {
        int col = colBase + wc * 64 + n * 16 + l15;
        colv[n] = col;
        py0v[n] = py0[col];
        py1v[n] = py1[col];
        py0C[n] = 0.636619772f * py0v[n];
        py1C[n] = 0.636619772f * py1v[n];
    }
    #pragma unroll
    for (int m = 0; m < 4; m++) {
        int row0 = rowBase + wr * 64 + m * 16 + lg * 4;
        #pragma unroll
        for (int j = 0; j < 4; j++) {
            int row = row0 + j;
            float a0 = px0[row], a1 = px1[row];
            #pragma unroll
            for (int n = 0; n < 4; n++) {
                float nngp = acc[m][n][j] * (1.0f / D_K);
                float ntk = nngp;
                layer_step(nngp, ntk, a0 * py0v[n], a0 * py0C[n]);
                layer_step(nngp, ntk, a1 * py1v[n], a1 * py1C[n]);
                __builtin_nontemporal_store(ntk, &out[(size_t)row * NROW + colv[n]]);
            }
        }
    }
}

extern "C" void kernel_launch(void* const* d_in, const int* in_sizes, int n_in,
                              void* d_out, int out_size, void* d_ws, size_t ws_size,
                              hipStream_t stream)
{
    const float* x = (const float*)d_in[0];
    const float* y = (const float*)d_in[1];
    float* out = (float*)d_out;

    char* ws = (char*)d_ws;
    unsigned short* xb = (unsigned short*)ws;
    unsigned short* yb = (unsigned short*)(ws + (size_t)8 * 1024 * 1024);
    float* px0 = (float*)(ws + (size_t)16 * 1024 * 1024);
    float* px1 = px0 + NROW;
    float* py0 = px1 + NROW;
    float* py1 = py0 + NROW;

    dim3 pgrid(NROW, 2);
    prep_kernel<<<pgrid, 256, 0, stream>>>(x, y, xb, yb, px0, px1, py0, py1);

    ntk_kernel<<<(NROW / BM) * (NROW / BN), 256, 0, stream>>>(xb, yb, px0, px1, py0, py1, out);
}